// Round 4
// baseline (922.316 us; speedup 1.0000x reference)
//
#include <hip/hip_runtime.h>
#include <math.h>

#define NB 8
#define NPTS 4096
#define NCH 64
#define NOUT 64
#define KNN 16

#define GLOBAL_AS const __attribute__((address_space(1)))
#define LDS_AS __attribute__((address_space(3)))

// ws layout in floats:
#define WS_SQ  0
#define WS_PT  (NB*NPTS)                       // 32768
#define WS_QT  (WS_PT + NB*NPTS*64)            // + 2097152
#define WS_IDX (WS_QT + NB*NPTS*64)            // int32 region, NB*NPTS*16 ints

// ---------------------------------------------------------------- K1: sq ----
__global__ __launch_bounds__(256) void k_sq(const float* __restrict__ fea,
                                            float* __restrict__ sq) {
    int g = blockIdx.x * 256 + threadIdx.x;      // 32768
    int b = g >> 12, n = g & 4095;
    const float* f = fea + (size_t)b * NCH * NPTS + n;
    float s = 0.f;
#pragma unroll
    for (int c = 0; c < NCH; ++c) s = fmaf(f[c * NPTS], f[c * NPTS], s);
    sq[g] = s;
}

// ------------------------------------------------------- K2: fused KNN ------
// 64 rows/block, gram tile 64x64 (4x4 register micro-tiles, fp32 VALU).
// colT double-buffered, prefetched via global_load_lds (width 16) one tile
// ahead -- staging latency hides under the gram. 2 barriers per tile:
//   B: lgkmcnt-only raw barrier (dist ds_writes -> scan ds_reads); must not
//      drain vmcnt or it would stall on the in-flight prefetch.
//   A: __syncthreads() at loop end; its vmcnt(0) drain doubles as the wait
//      for the prefetched colT of the next tile.
// Top-k per row in registers across lanes 0..15, ballot-filtered scan.
__global__ __launch_bounds__(256, 2) void k_knn(const float* __restrict__ fea,
                                                const float* __restrict__ sq,
                                                int* __restrict__ idxout) {
    __shared__ __align__(16) float rowT[64][64];     // [c][r]
    __shared__ __align__(16) float colT[2][64 * 64]; // [c][j] double buffer
    __shared__ __align__(16) float D[64 * 64];       // dist [r][col^swz(r)]

    const int b = blockIdx.y;
    const int n0 = blockIdx.x * 64;
    const int tid = threadIdx.x;
    const int to = tid & 15, tp = tid >> 4;
    const int lane = tid & 63, w = tid >> 6;
    const float* feab = fea + (size_t)b * NCH * NPTS;

    // async prefetch of colT[buf] for column tile at m0 (4 insts/wave)
    auto stage_async = [&](int buf, int m0) {
#pragma unroll
        for (int i = 0; i < 4; ++i) {
            int k = w * 4 + i;                       // chunk: c-rows 4k..4k+3
            int c = 4 * k + (lane >> 4);
            int j = (lane & 15) * 4;
            const float* gp = feab + c * NPTS + m0 + j;
            float* lp = &colT[buf][k * 256];         // wave-uniform base
            __builtin_amdgcn_global_load_lds((GLOBAL_AS void*)gp,
                                             (LDS_AS void*)lp, 16, 0, 0);
        }
    };

#pragma unroll
    for (int i = 0; i < 4; ++i) {
        int e = i * 1024 + tid * 4;
        int c = e >> 6, r = e & 63;
        *(float4*)&rowT[c][r] = *(const float4*)&feab[c * NPTS + n0 + r];
    }
    stage_async(0, 0);

    float lstv[16];                                  // row w*16+r, lanes 0..15
    int   lsti[16];
#pragma unroll
    for (int r = 0; r < 16; ++r) { lstv[r] = -3.0e38f; lsti[r] = 0; }

    __syncthreads();                                 // drains vmcnt too

    for (int t = 0; t < 64; ++t) {
        const int m0 = t * 64;
        const int cur = t & 1;
        if (t < 63) stage_async(cur ^ 1, m0 + 64);   // prefetch next tile

        float4 sqc = *(const float4*)&sq[b * NPTS + m0 + tp * 4];

        float acc[4][4] = {{0.f,0.f,0.f,0.f},{0.f,0.f,0.f,0.f},
                           {0.f,0.f,0.f,0.f},{0.f,0.f,0.f,0.f}};
#pragma unroll 8
        for (int c = 0; c < 64; ++c) {
            float4 rv = *(const float4*)&rowT[c][to * 4];
            float4 cv = *(const float4*)&colT[cur][c * 64 + tp * 4];
            float rr[4] = {rv.x, rv.y, rv.z, rv.w};
            float cc[4] = {cv.x, cv.y, cv.z, cv.w};
#pragma unroll
            for (int ri = 0; ri < 4; ++ri)
#pragma unroll
                for (int ci = 0; ci < 4; ++ci)
                    acc[ri][ci] = fmaf(rr[ri], cc[ci], acc[ri][ci]);
        }

        float sqa[4] = {sqc.x, sqc.y, sqc.z, sqc.w};
#pragma unroll
        for (int ri = 0; ri < 4; ++ri) {
            int row = to * 4 + ri;
            int colp = (tp * 4) ^ (((row >> 3) & 7) << 2);  // bits 0-1 kept
            float4 o;
            o.x = 2.f * acc[ri][0] - sqa[0];
            o.y = 2.f * acc[ri][1] - sqa[1];
            o.z = 2.f * acc[ri][2] - sqa[2];
            o.w = 2.f * acc[ri][3] - sqa[3];
            *(float4*)&D[row * 64 + colp] = o;
        }
        // barrier B: order ds_writes(D) -> ds_reads(D) WITHOUT draining vmcnt
        asm volatile("s_waitcnt lgkmcnt(0)\n\ts_barrier" ::: "memory");

#pragma unroll
        for (int r = 0; r < 16; ++r) {
            const int row = w * 16 + r;
            const int swz = ((row >> 3) & 7) << 2;
            float v = D[row * 64 + (lane ^ swz)];   // lane l = logical col l
            float thr = __shfl(lstv[r], 0);
            unsigned long long mask = __ballot(v > thr);
            while (mask) {                          // wave-uniform loop
                int src = __ffsll((unsigned long long)mask) - 1;
                mask &= mask - 1;
                float vv = __shfl(v, src);
                if (vv > thr) {                     // uniform branch
                    int col = m0 + src;
                    unsigned long long lt =
                        __ballot((lane < 16) && (lstv[r] < vv));
                    int p = __popcll(lt);           // insertion pos, p >= 1
                    float nv = __shfl_down(lstv[r], 1);
                    int   ni = __shfl_down(lsti[r], 1);
                    if (lane <= p - 2)      { lstv[r] = nv; lsti[r] = ni; }
                    else if (lane == p - 1) { lstv[r] = vv; lsti[r] = col; }
                    thr = __shfl(lstv[r], 0);
                }
            }
        }
        // barrier A: all waves done scanning D; vmcnt(0) drain here is the
        // completion wait for the prefetched colT[cur^1].
        __syncthreads();
    }

#pragma unroll
    for (int r = 0; r < 16; ++r) {                  // descending output
        int row = w * 16 + r;
        if (lane < 16)
            idxout[((size_t)(b * NPTS) + n0 + row) * KNN + (15 - lane)] = lsti[r];
    }
}

// ----------------------------------------------- K3: P/Q precompute ---------
__global__ __launch_bounds__(256) void k_pq(const float* __restrict__ fea,
                                            const float* __restrict__ Wf1,
                                            const float* __restrict__ bf1,
                                            float* __restrict__ Pt,
                                            float* __restrict__ Qt) {
    __shared__ __align__(16) float feaT[64][64];    // [c][n]
    __shared__ __align__(16) float WT[64][132];     // [c][o'], o' in 0..127
    __shared__ float sb[64];

    const int b = blockIdx.y;
    const int n0 = blockIdx.x * 64;
    const int tid = threadIdx.x;
    const int to = tid & 15, tn = tid >> 4;
    const float* feab = fea + (size_t)b * NCH * NPTS;

#pragma unroll
    for (int i = 0; i < 4; ++i) {
        int e = i * 1024 + tid * 4;
        int c = e >> 6, nn = e & 63;
        *(float4*)&feaT[c][nn] = *(const float4*)&feab[c * NPTS + n0 + nn];
    }
#pragma unroll
    for (int i = 0; i < 8; ++i) {
        int g = tid * 32 + i * 4;
        int op = g >> 6, c = g & 63;
        const float* src = (op < 64) ? &Wf1[op * 128 + c]
                                     : &Wf1[(op - 64) * 128 + 64 + c];
        float4 w = *(const float4*)src;
        WT[c + 0][op] = w.x; WT[c + 1][op] = w.y;
        WT[c + 2][op] = w.z; WT[c + 3][op] = w.w;
    }
    if (tid < 64) sb[tid] = bf1[tid];
    __syncthreads();

    float acc[4][8];
#pragma unroll
    for (int ni = 0; ni < 4; ++ni)
#pragma unroll
        for (int oj = 0; oj < 8; ++oj) acc[ni][oj] = 0.f;

#pragma unroll 4
    for (int c = 0; c < 64; ++c) {
        float4 a  = *(const float4*)&feaT[c][tn * 4];
        float4 w0 = *(const float4*)&WT[c][to * 8];
        float4 w1 = *(const float4*)&WT[c][to * 8 + 4];
        float av[4] = {a.x, a.y, a.z, a.w};
        float wv[8] = {w0.x, w0.y, w0.z, w0.w, w1.x, w1.y, w1.z, w1.w};
#pragma unroll
        for (int ni = 0; ni < 4; ++ni)
#pragma unroll
            for (int oj = 0; oj < 8; ++oj)
                acc[ni][oj] = fmaf(av[ni], wv[oj], acc[ni][oj]);
    }

    const int opb = to * 8;
#pragma unroll
    for (int ni = 0; ni < 4; ++ni) {
        int n = n0 + tn * 4 + ni;
        size_t base = ((size_t)b * NPTS + n) * 64;
        if (opb < 64) {     // P half: add bias
            float4 o0, o1;
            o0.x = acc[ni][0] + sb[opb + 0]; o0.y = acc[ni][1] + sb[opb + 1];
            o0.z = acc[ni][2] + sb[opb + 2]; o0.w = acc[ni][3] + sb[opb + 3];
            o1.x = acc[ni][4] + sb[opb + 4]; o1.y = acc[ni][5] + sb[opb + 5];
            o1.z = acc[ni][6] + sb[opb + 6]; o1.w = acc[ni][7] + sb[opb + 7];
            *(float4*)&Pt[base + opb]     = o0;
            *(float4*)&Pt[base + opb + 4] = o1;
        } else {            // Q half: no bias
            float4 o0, o1;
            o0.x = acc[ni][0]; o0.y = acc[ni][1]; o0.z = acc[ni][2]; o0.w = acc[ni][3];
            o1.x = acc[ni][4]; o1.y = acc[ni][5]; o1.z = acc[ni][6]; o1.w = acc[ni][7];
            *(float4*)&Qt[base + opb - 64]     = o0;
            *(float4*)&Qt[base + opb - 64 + 4] = o1;
        }
    }
}

// -------------------------------------------- K4: fused MLP + max ----------
__global__ __launch_bounds__(256) void k_mlp(
    const float* __restrict__ xyz,
    const float* __restrict__ Pt, const float* __restrict__ Qt,
    const int* __restrict__ knnidx,
    const float* __restrict__ Wg1, const float* __restrict__ bg1,
    const float* __restrict__ Wg2, const float* __restrict__ bg2,
    const float* __restrict__ Wf2, const float* __restrict__ bf2,
    const float* __restrict__ Wf3, const float* __restrict__ bf3,
    float* __restrict__ out) {
    __shared__ __align__(16) float bufX[64][68];
    __shared__ __align__(16) float bufY[64][68];
    __shared__ __align__(16) float Wbuf[64][68];
    __shared__ __align__(16) float scratch[1280];  // geo[10][68] then pm[64][17]
    __shared__ float biasS[64];
    __shared__ int sidx[64];

    const int b = blockIdx.y;
    const int n0 = blockIdx.x * 4;
    const int tid = threadIdx.x;
    const int to = tid & 15, tp = tid >> 4;

    if (tid < 64)
        sidx[tid] = knnidx[((size_t)(b * NPTS + n0)) * KNN + tid];
    __syncthreads();

    // f1 = relu(P + Q_gather) into bufX [c][pair]
    {
        int pair = tid >> 2, q = tid & 3;
        int m = sidx[pair];
        int pt = pair >> 4;
        const float* pB = &Pt[((size_t)b * NPTS + n0 + pt) * 64];
        const float* qB = &Qt[((size_t)b * NPTS + m) * 64];
#pragma unroll
        for (int i = 0; i < 4; ++i) {
            int c0 = q * 16 + i * 4;
            float4 pv = *(const float4*)&pB[c0];
            float4 qv = *(const float4*)&qB[c0];
            bufX[c0 + 0][pair] = fmaxf(pv.x + qv.x, 0.f);
            bufX[c0 + 1][pair] = fmaxf(pv.y + qv.y, 0.f);
            bufX[c0 + 2][pair] = fmaxf(pv.z + qv.z, 0.f);
            bufX[c0 + 3][pair] = fmaxf(pv.w + qv.w, 0.f);
        }
    }
    // geo [10][68] into scratch
    if (tid < 64) {
        int pair = tid, pt = pair >> 4;
        int m = sidx[pair];
        const float* xb = xyz + (size_t)b * 3 * NPTS;
        float cx = xb[0 * NPTS + n0 + pt], cy = xb[1 * NPTS + n0 + pt], cz = xb[2 * NPTS + n0 + pt];
        float kx = xb[0 * NPTS + m], ky = xb[1 * NPTS + m], kz = xb[2 * NPTS + m];
        float rx = cx - kx, ry = cy - ky, rz = cz - kz;
        float d = sqrtf(rx * rx + ry * ry + rz * rz);
        scratch[0 * 68 + pair] = d;
        scratch[1 * 68 + pair] = cx; scratch[2 * 68 + pair] = cy; scratch[3 * 68 + pair] = cz;
        scratch[4 * 68 + pair] = kx; scratch[5 * 68 + pair] = ky; scratch[6 * 68 + pair] = kz;
        scratch[7 * 68 + pair] = rx; scratch[8 * 68 + pair] = ry; scratch[9 * 68 + pair] = rz;
    }

    auto stageW = [&](const float* W, const float* bv) {
#pragma unroll
        for (int i = 0; i < 4; ++i) {
            int g = tid * 16 + i * 4;
            int o = g >> 6, c = g & 63;
            float4 w = *(const float4*)&W[g];
            Wbuf[c + 0][o] = w.x; Wbuf[c + 1][o] = w.y;
            Wbuf[c + 2][o] = w.z; Wbuf[c + 3][o] = w.w;
        }
        if (tid < 64) biasS[tid] = bv[tid];
    };

    auto gemmPh = [&](const float* src, float* dst, int Kdim) {
        float acc[4][4] = {{0.f,0.f,0.f,0.f},{0.f,0.f,0.f,0.f},
                           {0.f,0.f,0.f,0.f},{0.f,0.f,0.f,0.f}};
#pragma unroll 2
        for (int c = 0; c < Kdim; ++c) {
            float4 w = *(const float4*)&Wbuf[c][to * 4];
            float4 a = *(const float4*)(src + c * 68 + tp * 4);
            float wr[4] = {w.x, w.y, w.z, w.w};
            float ar[4] = {a.x, a.y, a.z, a.w};
#pragma unroll
            for (int oi = 0; oi < 4; ++oi)
#pragma unroll
                for (int pj = 0; pj < 4; ++pj)
                    acc[oi][pj] = fmaf(wr[oi], ar[pj], acc[oi][pj]);
        }
#pragma unroll
        for (int oi = 0; oi < 4; ++oi) {
            float bo = biasS[to * 4 + oi];
            float4 o4;
            o4.x = fmaxf(acc[oi][0] + bo, 0.f);
            o4.y = fmaxf(acc[oi][1] + bo, 0.f);
            o4.z = fmaxf(acc[oi][2] + bo, 0.f);
            o4.w = fmaxf(acc[oi][3] + bo, 0.f);
            *(float4*)(dst + (to * 4 + oi) * 68 + tp * 4) = o4;
        }
    };

    stageW(Wf2, bf2);
    __syncthreads();
    gemmPh(&bufX[0][0], &bufY[0][0], 64);       // f2
    __syncthreads();
    stageW(Wf3, bf3);
    __syncthreads();
    gemmPh(&bufY[0][0], &bufX[0][0], 64);       // f3 -> bufX
    __syncthreads();
    {   // Wg1 is 64x10
        for (int e = tid; e < 640; e += 256) {
            int o = e / 10, c = e - o * 10;
            Wbuf[c][o] = Wg1[e];
        }
        if (tid < 64) biasS[tid] = bg1[tid];
    }
    __syncthreads();
    gemmPh(scratch, &bufY[0][0], 10);           // g1 -> bufY
    __syncthreads();
    stageW(Wg2, bg2);
    __syncthreads();
    {   // g2 GEMM with fused *f3 and partial max epilogue
        float acc[4][4] = {{0.f,0.f,0.f,0.f},{0.f,0.f,0.f,0.f},
                           {0.f,0.f,0.f,0.f},{0.f,0.f,0.f,0.f}};
#pragma unroll 2
        for (int c = 0; c < 64; ++c) {
            float4 w = *(const float4*)&Wbuf[c][to * 4];
            float4 a = *(const float4*)&bufY[c][tp * 4];
            float wr[4] = {w.x, w.y, w.z, w.w};
            float ar[4] = {a.x, a.y, a.z, a.w};
#pragma unroll
            for (int oi = 0; oi < 4; ++oi)
#pragma unroll
                for (int pj = 0; pj < 4; ++pj)
                    acc[oi][pj] = fmaf(wr[oi], ar[pj], acc[oi][pj]);
        }
#pragma unroll
        for (int oi = 0; oi < 4; ++oi) {
            int o = to * 4 + oi;
            float bo = biasS[o];
            float mx = -3.0e38f;
#pragma unroll
            for (int pj = 0; pj < 4; ++pj) {
                float g2v = fmaxf(acc[oi][pj] + bo, 0.f);
                float f3v = bufX[o][tp * 4 + pj];
                mx = fmaxf(mx, g2v * f3v);
            }
            scratch[o * 17 + tp] = mx;          // pm[64][17]
        }
    }
    __syncthreads();
    {
        int o = tid & 63, pt = tid >> 6;
        float m0_ = scratch[o * 17 + pt * 4 + 0];
        float m1  = scratch[o * 17 + pt * 4 + 1];
        float m2  = scratch[o * 17 + pt * 4 + 2];
        float m3  = scratch[o * 17 + pt * 4 + 3];
        out[((size_t)b * 64 + o) * NPTS + n0 + pt] =
            fmaxf(fmaxf(m0_, m1), fmaxf(m2, m3));
    }
}

// ---------------------------------------------------------------------------
extern "C" void kernel_launch(void* const* d_in, const int* in_sizes, int n_in,
                              void* d_out, int out_size, void* d_ws, size_t ws_size,
                              hipStream_t stream) {
    const float* xyz = (const float*)d_in[0];
    const float* fea = (const float*)d_in[1];
    const float* Wg1 = (const float*)d_in[2];
    const float* bg1 = (const float*)d_in[3];
    const float* Wg2 = (const float*)d_in[4];
    const float* bg2 = (const float*)d_in[5];
    const float* Wf1 = (const float*)d_in[6];
    const float* bf1 = (const float*)d_in[7];
    const float* Wf2 = (const float*)d_in[8];
    const float* bf2 = (const float*)d_in[9];
    const float* Wf3 = (const float*)d_in[10];
    const float* bf3 = (const float*)d_in[11];
    float* out = (float*)d_out;
    float* ws = (float*)d_ws;

    float* sq = ws + WS_SQ;
    float* Pt = ws + WS_PT;
    float* Qt = ws + WS_QT;
    int* idxw = (int*)(ws + WS_IDX);

    k_sq <<<dim3(128),      dim3(256), 0, stream>>>(fea, sq);
    k_knn<<<dim3(64, 8),    dim3(256), 0, stream>>>(fea, sq, idxw);
    k_pq <<<dim3(64, 8),    dim3(256), 0, stream>>>(fea, Wf1, bf1, Pt, Qt);
    k_mlp<<<dim3(1024, 8),  dim3(256), 0, stream>>>(xyz, Pt, Qt, idxw,
                                                    Wg1, bg1, Wg2, bg2,
                                                    Wf2, bf2, Wf3, bf3, out);
}

// Round 5
// 759.156 us; speedup vs baseline: 1.2149x; 1.2149x over previous
//
#include <hip/hip_runtime.h>
#include <math.h>

#define NB 8
#define NPTS 4096
#define NCH 64
#define NOUT 64
#define KNN 16

#define GLOBAL_AS const __attribute__((address_space(1)))
#define LDS_AS __attribute__((address_space(3)))

// ws layout in floats:
#define WS_SQ  0
#define WS_PT  (NB*NPTS)                       // 32768
#define WS_QT  (WS_PT + NB*NPTS*64)            // + 2097152
#define WS_IDX (WS_QT + NB*NPTS*64)            // int32 region, NB*NPTS*16 ints

// ---------------------------------------------------------------- K1: sq ----
__global__ __launch_bounds__(256) void k_sq(const float* __restrict__ fea,
                                            float* __restrict__ sq) {
    int g = blockIdx.x * 256 + threadIdx.x;      // 32768
    int b = g >> 12, n = g & 4095;
    const float* f = fea + (size_t)b * NCH * NPTS + n;
    float s = 0.f;
#pragma unroll
    for (int c = 0; c < NCH; ++c) s = fmaf(f[c * NPTS], f[c * NPTS], s);
    sq[g] = s;
}

// ------------------------------------------------------- K2: fused KNN ------
// 64 rows/block, gram tile 64x64 (4x4 register micro-tiles, fp32 VALU).
// Scan redesign (r5): each wave = 4 lane-groups of 16; group g owns rows
// wbase+g*4+i (i=0..3), list of row i distributed across the group's 16
// lanes ascending (lane p = p-th smallest). Per tile, lane p reads logical
// cols 4p..4p+3 of its group's row as ONE ds_read_b128, pre-filters with
// max4 + one ballot per row; pops run in 4-group lockstep. Insertion:
// candidate float4 broadcast via 4 independent shfl (one latency),
// shfl_down of list issued in parallel with position ballot; thr kept
// stale inside the pop loop (inserting below current min is a no-op, so
// stale thr only wastes an iteration, never corrupts).
__global__ __launch_bounds__(256, 2) void k_knn(const float* __restrict__ fea,
                                                const float* __restrict__ sq,
                                                int* __restrict__ idxout) {
    __shared__ __align__(16) float rowT[64][64];     // [c][r]
    __shared__ __align__(16) float colT[2][64 * 64]; // [c][j] double buffer
    __shared__ __align__(16) float D[64 * 64];       // dist [r][col^swz4(r)]

    const int b = blockIdx.y;
    const int n0 = blockIdx.x * 64;
    const int tid = threadIdx.x;
    const int to = tid & 15, tp = tid >> 4;
    const int lane = tid & 63, w = tid >> 6;
    const int g = lane >> 4, p = lane & 15;
    const int wbase = w * 16;
    const float* feab = fea + (size_t)b * NCH * NPTS;

    // async prefetch of colT[buf] for column tile at m0 (4 insts/wave)
    auto stage_async = [&](int buf, int m0) {
#pragma unroll
        for (int i = 0; i < 4; ++i) {
            int k = w * 4 + i;                       // chunk: c-rows 4k..4k+3
            int c = 4 * k + (lane >> 4);
            int j = (lane & 15) * 4;
            const float* gp = feab + c * NPTS + m0 + j;
            float* lp = &colT[buf][k * 256];         // wave-uniform base
            __builtin_amdgcn_global_load_lds((GLOBAL_AS void*)gp,
                                             (LDS_AS void*)lp, 16, 0, 0);
        }
    };

#pragma unroll
    for (int i = 0; i < 4; ++i) {
        int e = i * 1024 + tid * 4;
        int c = e >> 6, r = e & 63;
        *(float4*)&rowT[c][r] = *(const float4*)&feab[c * NPTS + n0 + r];
    }
    stage_async(0, 0);

    float lstv[4];                                   // list of row wbase+g*4+i
    int   lsti[4];                                   // lane p = p-th smallest
#pragma unroll
    for (int i = 0; i < 4; ++i) { lstv[i] = -3.0e38f; lsti[i] = 0; }

    // single insert of (vv, col) into row-i list of this group (group-uniform)
    auto ins = [&](int i, float vv, int col) {
        unsigned long long lt = __ballot(lstv[i] < vv);
        int pos = __popc((unsigned)((lt >> (g * 16)) & 0xFFFFull));
        float nv = __shfl_down(lstv[i], 1, 16);
        int   ni = __shfl_down(lsti[i], 1, 16);
        if (p <= pos - 2)      { lstv[i] = nv; lsti[i] = ni; }
        else if (p == pos - 1) { lstv[i] = vv; lsti[i] = col; }
    };

    __syncthreads();                                 // drains vmcnt too

    for (int t = 0; t < 64; ++t) {
        const int m0 = t * 64;
        const int cur = t & 1;
        if (t < 63) stage_async(cur ^ 1, m0 + 64);   // prefetch next tile

        float4 sqc = *(const float4*)&sq[b * NPTS + m0 + tp * 4];

        float acc[4][4] = {{0.f,0.f,0.f,0.f},{0.f,0.f,0.f,0.f},
                           {0.f,0.f,0.f,0.f},{0.f,0.f,0.f,0.f}};
#pragma unroll 8
        for (int c = 0; c < 64; ++c) {
            float4 rv = *(const float4*)&rowT[c][to * 4];
            float4 cv = *(const float4*)&colT[cur][c * 64 + tp * 4];
            float rr[4] = {rv.x, rv.y, rv.z, rv.w};
            float cc[4] = {cv.x, cv.y, cv.z, cv.w};
#pragma unroll
            for (int ri = 0; ri < 4; ++ri)
#pragma unroll
                for (int ci = 0; ci < 4; ++ci)
                    acc[ri][ci] = fmaf(rr[ri], cc[ci], acc[ri][ci]);
        }

        float sqa[4] = {sqc.x, sqc.y, sqc.z, sqc.w};
#pragma unroll
        for (int ri = 0; ri < 4; ++ri) {
            int row = to * 4 + ri;
            int colp = (tp * 4) ^ (((row >> 2) & 15) << 2);  // bits 0-1 kept
            float4 o;
            o.x = 2.f * acc[ri][0] - sqa[0];
            o.y = 2.f * acc[ri][1] - sqa[1];
            o.z = 2.f * acc[ri][2] - sqa[2];
            o.w = 2.f * acc[ri][3] - sqa[3];
            *(float4*)&D[row * 64 + colp] = o;
        }
        // barrier B: order ds_writes(D) -> ds_reads(D) WITHOUT draining vmcnt
        asm volatile("s_waitcnt lgkmcnt(0)\n\ts_barrier" ::: "memory");

        // ---- scan: 4 rows per group in lockstep ----
        float4 dv[4];
        float thr[4];
#pragma unroll
        for (int i = 0; i < 4; ++i) {
            int row = wbase + g * 4 + i;
            int swz = ((row >> 2) & 15) << 2;
            dv[i] = *(const float4*)&D[row * 64 + ((p * 4) ^ swz)];
            thr[i] = __shfl(lstv[i], 0, 16);         // group-local min bcast
        }
#pragma unroll
        for (int i = 0; i < 4; ++i) {
            float vm = fmaxf(fmaxf(dv[i].x, dv[i].y), fmaxf(dv[i].z, dv[i].w));
            unsigned long long bal = __ballot(vm > thr[i]);
            unsigned mg = (unsigned)((bal >> (g * 16)) & 0xFFFFull);
            while (__any(mg != 0u)) {
                bool act = (mg != 0u);
                int srcp = act ? (__ffs(mg) - 1) : 0;
                mg &= (mg - 1u);                     // 0 stays 0
                int srcl = (g << 4) | srcp;
                float c0 = __shfl(dv[i].x, srcl);    // 4 independent bcasts
                float c1 = __shfl(dv[i].y, srcl);
                float c2 = __shfl(dv[i].z, srcl);
                float c3 = __shfl(dv[i].w, srcl);
                if (act) {
                    int cb = m0 + srcp * 4;
                    if (c0 > thr[i]) ins(i, c0, cb + 0);
                    if (c1 > thr[i]) ins(i, c1, cb + 1);
                    if (c2 > thr[i]) ins(i, c2, cb + 2);
                    if (c3 > thr[i]) ins(i, c3, cb + 3);
                }
            }
        }
        // barrier A: all waves done scanning D; vmcnt(0) drain here is the
        // completion wait for the prefetched colT[cur^1].
        __syncthreads();
    }

#pragma unroll
    for (int i = 0; i < 4; ++i) {                    // descending output
        int row = wbase + g * 4 + i;
        idxout[((size_t)(b * NPTS) + n0 + row) * KNN + (15 - p)] = lsti[i];
    }
}

// ----------------------------------------------- K3: P/Q precompute ---------
__global__ __launch_bounds__(256) void k_pq(const float* __restrict__ fea,
                                            const float* __restrict__ Wf1,
                                            const float* __restrict__ bf1,
                                            float* __restrict__ Pt,
                                            float* __restrict__ Qt) {
    __shared__ __align__(16) float feaT[64][64];    // [c][n]
    __shared__ __align__(16) float WT[64][132];     // [c][o'], o' in 0..127
    __shared__ float sb[64];

    const int b = blockIdx.y;
    const int n0 = blockIdx.x * 64;
    const int tid = threadIdx.x;
    const int to = tid & 15, tn = tid >> 4;
    const float* feab = fea + (size_t)b * NCH * NPTS;

#pragma unroll
    for (int i = 0; i < 4; ++i) {
        int e = i * 1024 + tid * 4;
        int c = e >> 6, nn = e & 63;
        *(float4*)&feaT[c][nn] = *(const float4*)&feab[c * NPTS + n0 + nn];
    }
#pragma unroll
    for (int i = 0; i < 8; ++i) {
        int g = tid * 32 + i * 4;
        int op = g >> 6, c = g & 63;
        const float* src = (op < 64) ? &Wf1[op * 128 + c]
                                     : &Wf1[(op - 64) * 128 + 64 + c];
        float4 w = *(const float4*)src;
        WT[c + 0][op] = w.x; WT[c + 1][op] = w.y;
        WT[c + 2][op] = w.z; WT[c + 3][op] = w.w;
    }
    if (tid < 64) sb[tid] = bf1[tid];
    __syncthreads();

    float acc[4][8];
#pragma unroll
    for (int ni = 0; ni < 4; ++ni)
#pragma unroll
        for (int oj = 0; oj < 8; ++oj) acc[ni][oj] = 0.f;

#pragma unroll 4
    for (int c = 0; c < 64; ++c) {
        float4 a  = *(const float4*)&feaT[c][tn * 4];
        float4 w0 = *(const float4*)&WT[c][to * 8];
        float4 w1 = *(const float4*)&WT[c][to * 8 + 4];
        float av[4] = {a.x, a.y, a.z, a.w};
        float wv[8] = {w0.x, w0.y, w0.z, w0.w, w1.x, w1.y, w1.z, w1.w};
#pragma unroll
        for (int ni = 0; ni < 4; ++ni)
#pragma unroll
            for (int oj = 0; oj < 8; ++oj)
                acc[ni][oj] = fmaf(av[ni], wv[oj], acc[ni][oj]);
    }

    const int opb = to * 8;
#pragma unroll
    for (int ni = 0; ni < 4; ++ni) {
        int n = n0 + tn * 4 + ni;
        size_t base = ((size_t)b * NPTS + n) * 64;
        if (opb < 64) {     // P half: add bias
            float4 o0, o1;
            o0.x = acc[ni][0] + sb[opb + 0]; o0.y = acc[ni][1] + sb[opb + 1];
            o0.z = acc[ni][2] + sb[opb + 2]; o0.w = acc[ni][3] + sb[opb + 3];
            o1.x = acc[ni][4] + sb[opb + 4]; o1.y = acc[ni][5] + sb[opb + 5];
            o1.z = acc[ni][6] + sb[opb + 6]; o1.w = acc[ni][7] + sb[opb + 7];
            *(float4*)&Pt[base + opb]     = o0;
            *(float4*)&Pt[base + opb + 4] = o1;
        } else {            // Q half: no bias
            float4 o0, o1;
            o0.x = acc[ni][0]; o0.y = acc[ni][1]; o0.z = acc[ni][2]; o0.w = acc[ni][3];
            o1.x = acc[ni][4]; o1.y = acc[ni][5]; o1.z = acc[ni][6]; o1.w = acc[ni][7];
            *(float4*)&Qt[base + opb - 64]     = o0;
            *(float4*)&Qt[base + opb - 64 + 4] = o1;
        }
    }
}

// -------------------------------------------- K4: fused MLP + max ----------
__global__ __launch_bounds__(256) void k_mlp(
    const float* __restrict__ xyz,
    const float* __restrict__ Pt, const float* __restrict__ Qt,
    const int* __restrict__ knnidx,
    const float* __restrict__ Wg1, const float* __restrict__ bg1,
    const float* __restrict__ Wg2, const float* __restrict__ bg2,
    const float* __restrict__ Wf2, const float* __restrict__ bf2,
    const float* __restrict__ Wf3, const float* __restrict__ bf3,
    float* __restrict__ out) {
    __shared__ __align__(16) float bufX[64][68];
    __shared__ __align__(16) float bufY[64][68];
    __shared__ __align__(16) float Wbuf[64][68];
    __shared__ __align__(16) float scratch[1280];  // geo[10][68] then pm[64][17]
    __shared__ float biasS[64];
    __shared__ int sidx[64];

    const int b = blockIdx.y;
    const int n0 = blockIdx.x * 4;
    const int tid = threadIdx.x;
    const int to = tid & 15, tp = tid >> 4;

    if (tid < 64)
        sidx[tid] = knnidx[((size_t)(b * NPTS + n0)) * KNN + tid];
    __syncthreads();

    // f1 = relu(P + Q_gather) into bufX [c][pair]
    {
        int pair = tid >> 2, q = tid & 3;
        int m = sidx[pair];
        int pt = pair >> 4;
        const float* pB = &Pt[((size_t)b * NPTS + n0 + pt) * 64];
        const float* qB = &Qt[((size_t)b * NPTS + m) * 64];
#pragma unroll
        for (int i = 0; i < 4; ++i) {
            int c0 = q * 16 + i * 4;
            float4 pv = *(const float4*)&pB[c0];
            float4 qv = *(const float4*)&qB[c0];
            bufX[c0 + 0][pair] = fmaxf(pv.x + qv.x, 0.f);
            bufX[c0 + 1][pair] = fmaxf(pv.y + qv.y, 0.f);
            bufX[c0 + 2][pair] = fmaxf(pv.z + qv.z, 0.f);
            bufX[c0 + 3][pair] = fmaxf(pv.w + qv.w, 0.f);
        }
    }
    // geo [10][68] into scratch
    if (tid < 64) {
        int pair = tid, pt = pair >> 4;
        int m = sidx[pair];
        const float* xb = xyz + (size_t)b * 3 * NPTS;
        float cx = xb[0 * NPTS + n0 + pt], cy = xb[1 * NPTS + n0 + pt], cz = xb[2 * NPTS + n0 + pt];
        float kx = xb[0 * NPTS + m], ky = xb[1 * NPTS + m], kz = xb[2 * NPTS + m];
        float rx = cx - kx, ry = cy - ky, rz = cz - kz;
        float d = sqrtf(rx * rx + ry * ry + rz * rz);
        scratch[0 * 68 + pair] = d;
        scratch[1 * 68 + pair] = cx; scratch[2 * 68 + pair] = cy; scratch[3 * 68 + pair] = cz;
        scratch[4 * 68 + pair] = kx; scratch[5 * 68 + pair] = ky; scratch[6 * 68 + pair] = kz;
        scratch[7 * 68 + pair] = rx; scratch[8 * 68 + pair] = ry; scratch[9 * 68 + pair] = rz;
    }

    auto stageW = [&](const float* W, const float* bv) {
#pragma unroll
        for (int i = 0; i < 4; ++i) {
            int g = tid * 16 + i * 4;
            int o = g >> 6, c = g & 63;
            float4 w = *(const float4*)&W[g];
            Wbuf[c + 0][o] = w.x; Wbuf[c + 1][o] = w.y;
            Wbuf[c + 2][o] = w.z; Wbuf[c + 3][o] = w.w;
        }
        if (tid < 64) biasS[tid] = bv[tid];
    };

    auto gemmPh = [&](const float* src, float* dst, int Kdim) {
        float acc[4][4] = {{0.f,0.f,0.f,0.f},{0.f,0.f,0.f,0.f},
                           {0.f,0.f,0.f,0.f},{0.f,0.f,0.f,0.f}};
#pragma unroll 2
        for (int c = 0; c < Kdim; ++c) {
            float4 w = *(const float4*)&Wbuf[c][to * 4];
            float4 a = *(const float4*)(src + c * 68 + tp * 4);
            float wr[4] = {w.x, w.y, w.z, w.w};
            float ar[4] = {a.x, a.y, a.z, a.w};
#pragma unroll
            for (int oi = 0; oi < 4; ++oi)
#pragma unroll
                for (int pj = 0; pj < 4; ++pj)
                    acc[oi][pj] = fmaf(wr[oi], ar[pj], acc[oi][pj]);
        }
#pragma unroll
        for (int oi = 0; oi < 4; ++oi) {
            float bo = biasS[to * 4 + oi];
            float4 o4;
            o4.x = fmaxf(acc[oi][0] + bo, 0.f);
            o4.y = fmaxf(acc[oi][1] + bo, 0.f);
            o4.z = fmaxf(acc[oi][2] + bo, 0.f);
            o4.w = fmaxf(acc[oi][3] + bo, 0.f);
            *(float4*)(dst + (to * 4 + oi) * 68 + tp * 4) = o4;
        }
    };

    stageW(Wf2, bf2);
    __syncthreads();
    gemmPh(&bufX[0][0], &bufY[0][0], 64);       // f2
    __syncthreads();
    stageW(Wf3, bf3);
    __syncthreads();
    gemmPh(&bufY[0][0], &bufX[0][0], 64);       // f3 -> bufX
    __syncthreads();
    {   // Wg1 is 64x10
        for (int e = tid; e < 640; e += 256) {
            int o = e / 10, c = e - o * 10;
            Wbuf[c][o] = Wg1[e];
        }
        if (tid < 64) biasS[tid] = bg1[tid];
    }
    __syncthreads();
    gemmPh(scratch, &bufY[0][0], 10);           // g1 -> bufY
    __syncthreads();
    stageW(Wg2, bg2);
    __syncthreads();
    {   // g2 GEMM with fused *f3 and partial max epilogue
        float acc[4][4] = {{0.f,0.f,0.f,0.f},{0.f,0.f,0.f,0.f},
                           {0.f,0.f,0.f,0.f},{0.f,0.f,0.f,0.f}};
#pragma unroll 2
        for (int c = 0; c < 64; ++c) {
            float4 w = *(const float4*)&Wbuf[c][to * 4];
            float4 a = *(const float4*)&bufY[c][tp * 4];
            float wr[4] = {w.x, w.y, w.z, w.w};
            float ar[4] = {a.x, a.y, a.z, a.w};
#pragma unroll
            for (int oi = 0; oi < 4; ++oi)
#pragma unroll
                for (int pj = 0; pj < 4; ++pj)
                    acc[oi][pj] = fmaf(wr[oi], ar[pj], acc[oi][pj]);
        }
#pragma unroll
        for (int oi = 0; oi < 4; ++oi) {
            int o = to * 4 + oi;
            float bo = biasS[o];
            float mx = -3.0e38f;
#pragma unroll
            for (int pj = 0; pj < 4; ++pj) {
                float g2v = fmaxf(acc[oi][pj] + bo, 0.f);
                float f3v = bufX[o][tp * 4 + pj];
                mx = fmaxf(mx, g2v * f3v);
            }
            scratch[o * 17 + tp] = mx;          // pm[64][17]
        }
    }
    __syncthreads();
    {
        int o = tid & 63, pt = tid >> 6;
        float m0_ = scratch[o * 17 + pt * 4 + 0];
        float m1  = scratch[o * 17 + pt * 4 + 1];
        float m2  = scratch[o * 17 + pt * 4 + 2];
        float m3  = scratch[o * 17 + pt * 4 + 3];
        out[((size_t)b * 64 + o) * NPTS + n0 + pt] =
            fmaxf(fmaxf(m0_, m1), fmaxf(m2, m3));
    }
}

// ---------------------------------------------------------------------------
extern "C" void kernel_launch(void* const* d_in, const int* in_sizes, int n_in,
                              void* d_out, int out_size, void* d_ws, size_t ws_size,
                              hipStream_t stream) {
    const float* xyz = (const float*)d_in[0];
    const float* fea = (const float*)d_in[1];
    const float* Wg1 = (const float*)d_in[2];
    const float* bg1 = (const float*)d_in[3];
    const float* Wg2 = (const float*)d_in[4];
    const float* bg2 = (const float*)d_in[5];
    const float* Wf1 = (const float*)d_in[6];
    const float* bf1 = (const float*)d_in[7];
    const float* Wf2 = (const float*)d_in[8];
    const float* bf2 = (const float*)d_in[9];
    const float* Wf3 = (const float*)d_in[10];
    const float* bf3 = (const float*)d_in[11];
    float* out = (float*)d_out;
    float* ws = (float*)d_ws;

    float* sq = ws + WS_SQ;
    float* Pt = ws + WS_PT;
    float* Qt = ws + WS_QT;
    int* idxw = (int*)(ws + WS_IDX);

    k_sq <<<dim3(128),      dim3(256), 0, stream>>>(fea, sq);
    k_knn<<<dim3(64, 8),    dim3(256), 0, stream>>>(fea, sq, idxw);
    k_pq <<<dim3(64, 8),    dim3(256), 0, stream>>>(fea, Wf1, bf1, Pt, Qt);
    k_mlp<<<dim3(1024, 8),  dim3(256), 0, stream>>>(xyz, Pt, Qt, idxw,
                                                    Wg1, bg1, Wg2, bg2,
                                                    Wf2, bf2, Wf3, bf3, out);
}

// Round 6
// 737.076 us; speedup vs baseline: 1.2513x; 1.0300x over previous
//
#include <hip/hip_runtime.h>
#include <math.h>

#define NB 8
#define NPTS 4096
#define NCH 64
#define NOUT 64
#define KNN 16

#define GLOBAL_AS const __attribute__((address_space(1)))
#define LDS_AS __attribute__((address_space(3)))

// ws layout in floats:
#define WS_SQ  0
#define WS_PT  (NB*NPTS)                       // 32768
#define WS_QT  (WS_PT + NB*NPTS*64)            // + 2097152
#define WS_IDX (WS_QT + NB*NPTS*64)            // int32 region, NB*NPTS*16 ints

// ---------------------------------------------------------------- K1: sq ----
__global__ __launch_bounds__(256) void k_sq(const float* __restrict__ fea,
                                            float* __restrict__ sq) {
    int g = blockIdx.x * 256 + threadIdx.x;      // 32768
    int b = g >> 12, n = g & 4095;
    const float* f = fea + (size_t)b * NCH * NPTS + n;
    float s = 0.f;
#pragma unroll
    for (int c = 0; c < NCH; ++c) s = fmaf(f[c * NPTS], f[c * NPTS], s);
    sq[g] = s;
}

// ------------------------------------------------------- K2: fused KNN ------
// r6 restructure: each WAVE owns 16 rows (w*16..w*16+15). Lane (g,p)
// accumulates acc[i][j] = (row w*16+g*4+i, col p*4+j) -- the gram output
// layout IS the scan layout, so the dist matrix D, its LDS round-trip and
// barrier B are all deleted. One barrier per tile. LDS 48KB -> 3 blocks/CU.
// Top-k lists unchanged: ascending across the 16 lanes of each group,
// ballot-filtered lockstep pops, stale-thr-tolerant insertion.
__global__ __launch_bounds__(256, 2) void k_knn(const float* __restrict__ fea,
                                                const float* __restrict__ sq,
                                                int* __restrict__ idxout) {
    __shared__ __align__(16) float rowT[64][64];     // [c][r] 16K
    __shared__ __align__(16) float colT[2][64 * 64]; // [c][j] dbuf 32K

    const int b = blockIdx.y;
    const int n0 = blockIdx.x * 64;
    const int tid = threadIdx.x;
    const int lane = tid & 63, w = tid >> 6;
    const int g = lane >> 4, p = lane & 15;
    const int rbase = w * 16 + g * 4;                // this lane's 4 rows
    const float* feab = fea + (size_t)b * NCH * NPTS;

    // async prefetch of colT[buf] for column tile at m0 (4 insts/wave)
    auto stage_async = [&](int buf, int m0) {
#pragma unroll
        for (int i = 0; i < 4; ++i) {
            int k = w * 4 + i;                       // chunk: c-rows 4k..4k+3
            int c = 4 * k + (lane >> 4);
            int j = (lane & 15) * 4;
            const float* gp = feab + c * NPTS + m0 + j;
            float* lp = &colT[buf][k * 256];         // wave-uniform base
            __builtin_amdgcn_global_load_lds((GLOBAL_AS void*)gp,
                                             (LDS_AS void*)lp, 16, 0, 0);
        }
    };

#pragma unroll
    for (int i = 0; i < 4; ++i) {
        int e = i * 1024 + tid * 4;
        int c = e >> 6, r = e & 63;
        *(float4*)&rowT[c][r] = *(const float4*)&feab[c * NPTS + n0 + r];
    }
    stage_async(0, 0);

    float lstv[4];                                   // row rbase+i list
    int   lsti[4];                                   // lane p = p-th smallest
#pragma unroll
    for (int i = 0; i < 4; ++i) { lstv[i] = -3.0e38f; lsti[i] = 0; }

    // single insert of (vv, col) into row-i list of this group (group-uniform)
    auto ins = [&](int i, float vv, int col) {
        unsigned long long lt = __ballot(lstv[i] < vv);
        int pos = __popc((unsigned)((lt >> (g * 16)) & 0xFFFFull));
        float nv = __shfl_down(lstv[i], 1, 16);
        int   ni = __shfl_down(lsti[i], 1, 16);
        if (p <= pos - 2)      { lstv[i] = nv; lsti[i] = ni; }
        else if (p == pos - 1) { lstv[i] = vv; lsti[i] = col; }
    };

    __syncthreads();                                 // drains vmcnt too

    for (int t = 0; t < 64; ++t) {
        const int m0 = t * 64;
        const int cur = t & 1;
        if (t < 63) stage_async(cur ^ 1, m0 + 64);   // prefetch next tile

        float4 sqc = *(const float4*)&sq[b * NPTS + m0 + p * 4];

        float acc[4][4] = {{0.f,0.f,0.f,0.f},{0.f,0.f,0.f,0.f},
                           {0.f,0.f,0.f,0.f},{0.f,0.f,0.f,0.f}};
#pragma unroll 8
        for (int c = 0; c < 64; ++c) {
            float4 rv = *(const float4*)&rowT[c][rbase];
            float4 cv = *(const float4*)&colT[cur][c * 64 + p * 4];
            float rr[4] = {rv.x, rv.y, rv.z, rv.w};
            float cc[4] = {cv.x, cv.y, cv.z, cv.w};
#pragma unroll
            for (int ri = 0; ri < 4; ++ri)
#pragma unroll
                for (int ci = 0; ci < 4; ++ci)
                    acc[ri][ci] = fmaf(rr[ri], cc[ci], acc[ri][ci]);
        }

        // transform in place: dist row rbase+i, cols p*4..p*4+3
        float thr[4];
#pragma unroll
        for (int i = 0; i < 4; ++i) {
            acc[i][0] = 2.f * acc[i][0] - sqc.x;
            acc[i][1] = 2.f * acc[i][1] - sqc.y;
            acc[i][2] = 2.f * acc[i][2] - sqc.z;
            acc[i][3] = 2.f * acc[i][3] - sqc.w;
            thr[i] = __shfl(lstv[i], 0, 16);         // group-local min bcast
        }

#pragma unroll
        for (int i = 0; i < 4; ++i) {
            float vm = fmaxf(fmaxf(acc[i][0], acc[i][1]),
                             fmaxf(acc[i][2], acc[i][3]));
            unsigned long long bal = __ballot(vm > thr[i]);
            unsigned mg = (unsigned)((bal >> (g * 16)) & 0xFFFFull);
            while (__any(mg != 0u)) {
                bool act = (mg != 0u);
                int srcp = act ? (__ffs(mg) - 1) : 0;
                mg &= (mg - 1u);                     // 0 stays 0
                int srcl = (g << 4) | srcp;
                float c0 = __shfl(acc[i][0], srcl);  // 4 independent bcasts
                float c1 = __shfl(acc[i][1], srcl);
                float c2 = __shfl(acc[i][2], srcl);
                float c3 = __shfl(acc[i][3], srcl);
                if (act) {
                    int cb = m0 + srcp * 4;
                    if (c0 > thr[i]) ins(i, c0, cb + 0);
                    if (c1 > thr[i]) ins(i, c1, cb + 1);
                    if (c2 > thr[i]) ins(i, c2, cb + 2);
                    if (c3 > thr[i]) ins(i, c3, cb + 3);
                }
            }
        }
        // one barrier per tile: everyone done reading colT[cur]; the implicit
        // vmcnt(0) drain is the completion wait for the prefetched colT[cur^1].
        __syncthreads();
    }

#pragma unroll
    for (int i = 0; i < 4; ++i) {                    // descending output
        int row = rbase + i;
        idxout[((size_t)(b * NPTS) + n0 + row) * KNN + (15 - p)] = lsti[i];
    }
}

// ----------------------------------------------- K3: P/Q precompute ---------
__global__ __launch_bounds__(256) void k_pq(const float* __restrict__ fea,
                                            const float* __restrict__ Wf1,
                                            const float* __restrict__ bf1,
                                            float* __restrict__ Pt,
                                            float* __restrict__ Qt) {
    __shared__ __align__(16) float feaT[64][64];    // [c][n]
    __shared__ __align__(16) float WT[64][132];     // [c][o'], o' in 0..127
    __shared__ float sb[64];

    const int b = blockIdx.y;
    const int n0 = blockIdx.x * 64;
    const int tid = threadIdx.x;
    const int to = tid & 15, tn = tid >> 4;
    const float* feab = fea + (size_t)b * NCH * NPTS;

#pragma unroll
    for (int i = 0; i < 4; ++i) {
        int e = i * 1024 + tid * 4;
        int c = e >> 6, nn = e & 63;
        *(float4*)&feaT[c][nn] = *(const float4*)&feab[c * NPTS + n0 + nn];
    }
#pragma unroll
    for (int i = 0; i < 8; ++i) {
        int g = tid * 32 + i * 4;
        int op = g >> 6, c = g & 63;
        const float* src = (op < 64) ? &Wf1[op * 128 + c]
                                     : &Wf1[(op - 64) * 128 + 64 + c];
        float4 w = *(const float4*)src;
        WT[c + 0][op] = w.x; WT[c + 1][op] = w.y;
        WT[c + 2][op] = w.z; WT[c + 3][op] = w.w;
    }
    if (tid < 64) sb[tid] = bf1[tid];
    __syncthreads();

    float acc[4][8];
#pragma unroll
    for (int ni = 0; ni < 4; ++ni)
#pragma unroll
        for (int oj = 0; oj < 8; ++oj) acc[ni][oj] = 0.f;

#pragma unroll 4
    for (int c = 0; c < 64; ++c) {
        float4 a  = *(const float4*)&feaT[c][tn * 4];
        float4 w0 = *(const float4*)&WT[c][to * 8];
        float4 w1 = *(const float4*)&WT[c][to * 8 + 4];
        float av[4] = {a.x, a.y, a.z, a.w};
        float wv[8] = {w0.x, w0.y, w0.z, w0.w, w1.x, w1.y, w1.z, w1.w};
#pragma unroll
        for (int ni = 0; ni < 4; ++ni)
#pragma unroll
            for (int oj = 0; oj < 8; ++oj)
                acc[ni][oj] = fmaf(av[ni], wv[oj], acc[ni][oj]);
    }

    const int opb = to * 8;
#pragma unroll
    for (int ni = 0; ni < 4; ++ni) {
        int n = n0 + tn * 4 + ni;
        size_t base = ((size_t)b * NPTS + n) * 64;
        if (opb < 64) {     // P half: add bias
            float4 o0, o1;
            o0.x = acc[ni][0] + sb[opb + 0]; o0.y = acc[ni][1] + sb[opb + 1];
            o0.z = acc[ni][2] + sb[opb + 2]; o0.w = acc[ni][3] + sb[opb + 3];
            o1.x = acc[ni][4] + sb[opb + 4]; o1.y = acc[ni][5] + sb[opb + 5];
            o1.z = acc[ni][6] + sb[opb + 6]; o1.w = acc[ni][7] + sb[opb + 7];
            *(float4*)&Pt[base + opb]     = o0;
            *(float4*)&Pt[base + opb + 4] = o1;
        } else {            // Q half: no bias
            float4 o0, o1;
            o0.x = acc[ni][0]; o0.y = acc[ni][1]; o0.z = acc[ni][2]; o0.w = acc[ni][3];
            o1.x = acc[ni][4]; o1.y = acc[ni][5]; o1.z = acc[ni][6]; o1.w = acc[ni][7];
            *(float4*)&Qt[base + opb - 64]     = o0;
            *(float4*)&Qt[base + opb - 64 + 4] = o1;
        }
    }
}

// -------------------------------------------- K4: fused MLP + max ----------
__global__ __launch_bounds__(256) void k_mlp(
    const float* __restrict__ xyz,
    const float* __restrict__ Pt, const float* __restrict__ Qt,
    const int* __restrict__ knnidx,
    const float* __restrict__ Wg1, const float* __restrict__ bg1,
    const float* __restrict__ Wg2, const float* __restrict__ bg2,
    const float* __restrict__ Wf2, const float* __restrict__ bf2,
    const float* __restrict__ Wf3, const float* __restrict__ bf3,
    float* __restrict__ out) {
    __shared__ __align__(16) float bufX[64][68];
    __shared__ __align__(16) float bufY[64][68];
    __shared__ __align__(16) float Wbuf[64][68];
    __shared__ __align__(16) float scratch[1280];  // geo[10][68] then pm[64][17]
    __shared__ float biasS[64];
    __shared__ int sidx[64];

    const int b = blockIdx.y;
    const int n0 = blockIdx.x * 4;
    const int tid = threadIdx.x;
    const int to = tid & 15, tp = tid >> 4;

    if (tid < 64)
        sidx[tid] = knnidx[((size_t)(b * NPTS + n0)) * KNN + tid];
    __syncthreads();

    // f1 = relu(P + Q_gather) into bufX [c][pair]
    {
        int pair = tid >> 2, q = tid & 3;
        int m = sidx[pair];
        int pt = pair >> 4;
        const float* pB = &Pt[((size_t)b * NPTS + n0 + pt) * 64];
        const float* qB = &Qt[((size_t)b * NPTS + m) * 64];
#pragma unroll
        for (int i = 0; i < 4; ++i) {
            int c0 = q * 16 + i * 4;
            float4 pv = *(const float4*)&pB[c0];
            float4 qv = *(const float4*)&qB[c0];
            bufX[c0 + 0][pair] = fmaxf(pv.x + qv.x, 0.f);
            bufX[c0 + 1][pair] = fmaxf(pv.y + qv.y, 0.f);
            bufX[c0 + 2][pair] = fmaxf(pv.z + qv.z, 0.f);
            bufX[c0 + 3][pair] = fmaxf(pv.w + qv.w, 0.f);
        }
    }
    // geo [10][68] into scratch
    if (tid < 64) {
        int pair = tid, pt = pair >> 4;
        int m = sidx[pair];
        const float* xb = xyz + (size_t)b * 3 * NPTS;
        float cx = xb[0 * NPTS + n0 + pt], cy = xb[1 * NPTS + n0 + pt], cz = xb[2 * NPTS + n0 + pt];
        float kx = xb[0 * NPTS + m], ky = xb[1 * NPTS + m], kz = xb[2 * NPTS + m];
        float rx = cx - kx, ry = cy - ky, rz = cz - kz;
        float d = sqrtf(rx * rx + ry * ry + rz * rz);
        scratch[0 * 68 + pair] = d;
        scratch[1 * 68 + pair] = cx; scratch[2 * 68 + pair] = cy; scratch[3 * 68 + pair] = cz;
        scratch[4 * 68 + pair] = kx; scratch[5 * 68 + pair] = ky; scratch[6 * 68 + pair] = kz;
        scratch[7 * 68 + pair] = rx; scratch[8 * 68 + pair] = ry; scratch[9 * 68 + pair] = rz;
    }

    auto stageW = [&](const float* W, const float* bv) {
#pragma unroll
        for (int i = 0; i < 4; ++i) {
            int g = tid * 16 + i * 4;
            int o = g >> 6, c = g & 63;
            float4 w = *(const float4*)&W[g];
            Wbuf[c + 0][o] = w.x; Wbuf[c + 1][o] = w.y;
            Wbuf[c + 2][o] = w.z; Wbuf[c + 3][o] = w.w;
        }
        if (tid < 64) biasS[tid] = bv[tid];
    };

    auto gemmPh = [&](const float* src, float* dst, int Kdim) {
        float acc[4][4] = {{0.f,0.f,0.f,0.f},{0.f,0.f,0.f,0.f},
                           {0.f,0.f,0.f,0.f},{0.f,0.f,0.f,0.f}};
#pragma unroll 2
        for (int c = 0; c < Kdim; ++c) {
            float4 w = *(const float4*)&Wbuf[c][to * 4];
            float4 a = *(const float4*)(src + c * 68 + tp * 4);
            float wr[4] = {w.x, w.y, w.z, w.w};
            float ar[4] = {a.x, a.y, a.z, a.w};
#pragma unroll
            for (int oi = 0; oi < 4; ++oi)
#pragma unroll
                for (int pj = 0; pj < 4; ++pj)
                    acc[oi][pj] = fmaf(wr[oi], ar[pj], acc[oi][pj]);
        }
#pragma unroll
        for (int oi = 0; oi < 4; ++oi) {
            float bo = biasS[to * 4 + oi];
            float4 o4;
            o4.x = fmaxf(acc[oi][0] + bo, 0.f);
            o4.y = fmaxf(acc[oi][1] + bo, 0.f);
            o4.z = fmaxf(acc[oi][2] + bo, 0.f);
            o4.w = fmaxf(acc[oi][3] + bo, 0.f);
            *(float4*)(dst + (to * 4 + oi) * 68 + tp * 4) = o4;
        }
    };

    stageW(Wf2, bf2);
    __syncthreads();
    gemmPh(&bufX[0][0], &bufY[0][0], 64);       // f2
    __syncthreads();
    stageW(Wf3, bf3);
    __syncthreads();
    gemmPh(&bufY[0][0], &bufX[0][0], 64);       // f3 -> bufX
    __syncthreads();
    {   // Wg1 is 64x10
        for (int e = tid; e < 640; e += 256) {
            int o = e / 10, c = e - o * 10;
            Wbuf[c][o] = Wg1[e];
        }
        if (tid < 64) biasS[tid] = bg1[tid];
    }
    __syncthreads();
    gemmPh(scratch, &bufY[0][0], 10);           // g1 -> bufY
    __syncthreads();
    stageW(Wg2, bg2);
    __syncthreads();
    {   // g2 GEMM with fused *f3 and partial max epilogue
        float acc[4][4] = {{0.f,0.f,0.f,0.f},{0.f,0.f,0.f,0.f},
                           {0.f,0.f,0.f,0.f},{0.f,0.f,0.f,0.f}};
#pragma unroll 2
        for (int c = 0; c < 64; ++c) {
            float4 w = *(const float4*)&Wbuf[c][to * 4];
            float4 a = *(const float4*)&bufY[c][tp * 4];
            float wr[4] = {w.x, w.y, w.z, w.w};
            float ar[4] = {a.x, a.y, a.z, a.w};
#pragma unroll
            for (int oi = 0; oi < 4; ++oi)
#pragma unroll
                for (int pj = 0; pj < 4; ++pj)
                    acc[oi][pj] = fmaf(wr[oi], ar[pj], acc[oi][pj]);
        }
#pragma unroll
        for (int oi = 0; oi < 4; ++oi) {
            int o = to * 4 + oi;
            float bo = biasS[o];
            float mx = -3.0e38f;
#pragma unroll
            for (int pj = 0; pj < 4; ++pj) {
                float g2v = fmaxf(acc[oi][pj] + bo, 0.f);
                float f3v = bufX[o][tp * 4 + pj];
                mx = fmaxf(mx, g2v * f3v);
            }
            scratch[o * 17 + tp] = mx;          // pm[64][17]
        }
    }
    __syncthreads();
    {
        int o = tid & 63, pt = tid >> 6;
        float m0_ = scratch[o * 17 + pt * 4 + 0];
        float m1  = scratch[o * 17 + pt * 4 + 1];
        float m2  = scratch[o * 17 + pt * 4 + 2];
        float m3  = scratch[o * 17 + pt * 4 + 3];
        out[((size_t)b * 64 + o) * NPTS + n0 + pt] =
            fmaxf(fmaxf(m0_, m1), fmaxf(m2, m3));
    }
}

// ---------------------------------------------------------------------------
extern "C" void kernel_launch(void* const* d_in, const int* in_sizes, int n_in,
                              void* d_out, int out_size, void* d_ws, size_t ws_size,
                              hipStream_t stream) {
    const float* xyz = (const float*)d_in[0];
    const float* fea = (const float*)d_in[1];
    const float* Wg1 = (const float*)d_in[2];
    const float* bg1 = (const float*)d_in[3];
    const float* Wg2 = (const float*)d_in[4];
    const float* bg2 = (const float*)d_in[5];
    const float* Wf1 = (const float*)d_in[6];
    const float* bf1 = (const float*)d_in[7];
    const float* Wf2 = (const float*)d_in[8];
    const float* bf2 = (const float*)d_in[9];
    const float* Wf3 = (const float*)d_in[10];
    const float* bf3 = (const float*)d_in[11];
    float* out = (float*)d_out;
    float* ws = (float*)d_ws;

    float* sq = ws + WS_SQ;
    float* Pt = ws + WS_PT;
    float* Qt = ws + WS_QT;
    int* idxw = (int*)(ws + WS_IDX);

    k_sq <<<dim3(128),      dim3(256), 0, stream>>>(fea, sq);
    k_knn<<<dim3(64, 8),    dim3(256), 0, stream>>>(fea, sq, idxw);
    k_pq <<<dim3(64, 8),    dim3(256), 0, stream>>>(fea, Wf1, bf1, Pt, Qt);
    k_mlp<<<dim3(1024, 8),  dim3(256), 0, stream>>>(xyz, Pt, Qt, idxw,
                                                    Wg1, bg1, Wg2, bg2,
                                                    Wf2, bf2, Wf3, bf3, out);
}

// Round 7
// 734.694 us; speedup vs baseline: 1.2554x; 1.0032x over previous
//
#include <hip/hip_runtime.h>
#include <math.h>

#define NB 8
#define NPTS 4096
#define NCH 64
#define NOUT 64
#define KNN 16

#define GLOBAL_AS const __attribute__((address_space(1)))
#define LDS_AS __attribute__((address_space(3)))

// ws layout in floats:
#define WS_SQ  0
#define WS_PT  (NB*NPTS)                       // 32768
#define WS_QT  (WS_PT + NB*NPTS*64)            // + 2097152
#define WS_IDX (WS_QT + NB*NPTS*64)            // int32 region, NB*NPTS*16 ints

// ---------------------------------------------------------------- K1: sq ----
__global__ __launch_bounds__(256) void k_sq(const float* __restrict__ fea,
                                            float* __restrict__ sq) {
    int g = blockIdx.x * 256 + threadIdx.x;      // 32768
    int b = g >> 12, n = g & 4095;
    const float* f = fea + (size_t)b * NCH * NPTS + n;
    float s = 0.f;
#pragma unroll
    for (int c = 0; c < NCH; ++c) s = fmaf(f[c * NPTS], f[c * NPTS], s);
    sq[g] = s;
}

// ------------------------------------------------------- K2: fused KNN ------
// r7: 128-column tiles, acc[4][8] micro-tile. Wave owns 16 rows (4 groups of
// 16 lanes x 4 rows); lane (g,p) holds rows rbase..rbase+3, cols p*4..+3 and
// 64+p*4..+3. LDS instr per FMA drops 1.5x (3 ds_reads / 32 FMA), barriers
// halve (32/block). colT double-buffered via global_load_lds prefetch; LDS
// 16K rowT + 64K colT = 80KB, exact 2-blocks/CU fit. Scan: same ballot-
// filtered lockstep pops, looped over the 2 column halves; thr persistent
// across tiles (re-broadcast only after an insertion).
__global__ __launch_bounds__(256, 2) void k_knn(const float* __restrict__ fea,
                                                const float* __restrict__ sq,
                                                int* __restrict__ idxout) {
    __shared__ __align__(16) float rowT[64][64];      // 16KB
    __shared__ __align__(16) float colT[2][64 * 128]; // 64KB dbuf

    const int b = blockIdx.y;
    const int n0 = blockIdx.x * 64;
    const int tid = threadIdx.x;
    const int lane = tid & 63, w = tid >> 6;
    const int g = lane >> 4, p = lane & 15;
    const int rbase = w * 16 + g * 4;                 // this lane's 4 rows
    const float* feab = fea + (size_t)b * NCH * NPTS;

    // async prefetch of colT[buf] (64ch x 128 cols) for tile at m0; 8/wave
    auto stage_async = [&](int buf, int m0) {
#pragma unroll
        for (int i = 0; i < 8; ++i) {
            int k = w * 8 + i;                        // chunk: 256 floats
            int c = 2 * k + (lane >> 5);
            int j = (lane & 31) * 4;
            const float* gp = feab + c * NPTS + m0 + j;
            float* lp = &colT[buf][k * 256];          // wave-uniform base
            __builtin_amdgcn_global_load_lds((GLOBAL_AS void*)gp,
                                             (LDS_AS void*)lp, 16, 0, 0);
        }
    };

#pragma unroll
    for (int i = 0; i < 4; ++i) {
        int e = i * 1024 + tid * 4;
        int c = e >> 6, r = e & 63;
        *(float4*)&rowT[c][r] = *(const float4*)&feab[c * NPTS + n0 + r];
    }
    stage_async(0, 0);

    float lstv[4];                                    // row rbase+i list
    int   lsti[4];                                    // lane p = p-th smallest
    float thr[4];                                     // persistent list-min
#pragma unroll
    for (int i = 0; i < 4; ++i) {
        lstv[i] = -3.0e38f; lsti[i] = 0; thr[i] = -3.0e38f;
    }

    // single insert of (vv, col) into row-i list of this group (group-uniform)
    auto ins = [&](int i, float vv, int col) {
        unsigned long long lt = __ballot(lstv[i] < vv);
        int pos = __popc((unsigned)((lt >> (g * 16)) & 0xFFFFull));
        float nv = __shfl_down(lstv[i], 1, 16);
        int   ni = __shfl_down(lsti[i], 1, 16);
        if (p <= pos - 2)      { lstv[i] = nv; lsti[i] = ni; }
        else if (p == pos - 1) { lstv[i] = vv; lsti[i] = col; }
    };

    __syncthreads();                                  // drains vmcnt too

    for (int t = 0; t < 32; ++t) {
        const int m0 = t * 128;
        const int cur = t & 1;
        if (t < 31) stage_async(cur ^ 1, m0 + 128);   // prefetch next tile

        float4 sql = *(const float4*)&sq[b * NPTS + m0 + p * 4];
        float4 sqh = *(const float4*)&sq[b * NPTS + m0 + 64 + p * 4];

        float acc[4][8];
#pragma unroll
        for (int i = 0; i < 4; ++i)
#pragma unroll
            for (int j = 0; j < 8; ++j) acc[i][j] = 0.f;

#pragma unroll 4
        for (int c = 0; c < 64; ++c) {
            float4 rv  = *(const float4*)&rowT[c][rbase];
            float4 cv0 = *(const float4*)&colT[cur][c * 128 + p * 4];
            float4 cv1 = *(const float4*)&colT[cur][c * 128 + 64 + p * 4];
            float rr[4] = {rv.x, rv.y, rv.z, rv.w};
            float c0[4] = {cv0.x, cv0.y, cv0.z, cv0.w};
            float c1[4] = {cv1.x, cv1.y, cv1.z, cv1.w};
#pragma unroll
            for (int ri = 0; ri < 4; ++ri) {
#pragma unroll
                for (int cj = 0; cj < 4; ++cj) {
                    acc[ri][cj]     = fmaf(rr[ri], c0[cj], acc[ri][cj]);
                    acc[ri][cj + 4] = fmaf(rr[ri], c1[cj], acc[ri][cj + 4]);
                }
            }
        }

        // transform: dist = 2*G - sq[col]
        float sqa[8] = {sql.x, sql.y, sql.z, sql.w, sqh.x, sqh.y, sqh.z, sqh.w};
#pragma unroll
        for (int i = 0; i < 4; ++i)
#pragma unroll
            for (int j = 0; j < 8; ++j)
                acc[i][j] = fmaf(2.f, acc[i][j], -sqa[j]);

        // ---- scan: per row, per 64-col half; lockstep pops across groups ----
#pragma unroll
        for (int i = 0; i < 4; ++i) {
#pragma unroll
            for (int h = 0; h < 2; ++h) {
                float v0 = acc[i][h * 4 + 0], v1 = acc[i][h * 4 + 1];
                float v2 = acc[i][h * 4 + 2], v3 = acc[i][h * 4 + 3];
                float vm = fmaxf(fmaxf(v0, v1), fmaxf(v2, v3));
                unsigned long long bal = __ballot(vm > thr[i]);
                unsigned mg = (unsigned)((bal >> (g * 16)) & 0xFFFFull);
                while (__any(mg != 0u)) {
                    bool act = (mg != 0u);
                    int srcp = act ? (__ffs(mg) - 1) : 0;
                    mg &= (mg - 1u);                  // 0 stays 0
                    int srcl = (g << 4) | srcp;
                    float b0 = __shfl(v0, srcl);      // 4 independent bcasts
                    float b1 = __shfl(v1, srcl);
                    float b2 = __shfl(v2, srcl);
                    float b3 = __shfl(v3, srcl);
                    if (act) {
                        int cb = m0 + h * 64 + srcp * 4;
                        if (b0 > thr[i]) ins(i, b0, cb + 0);
                        if (b1 > thr[i]) ins(i, b1, cb + 1);
                        if (b2 > thr[i]) ins(i, b2, cb + 2);
                        if (b3 > thr[i]) ins(i, b3, cb + 3);
                    }
                }
                if (bal) thr[i] = __shfl(lstv[i], 0, 16);  // refresh after ins
            }
        }
        // one barrier per tile; implicit vmcnt(0) drain completes the
        // prefetched colT[cur^1].
        __syncthreads();
    }

#pragma unroll
    for (int i = 0; i < 4; ++i) {                     // descending output
        int row = rbase + i;
        idxout[((size_t)(b * NPTS) + n0 + row) * KNN + (15 - p)] = lsti[i];
    }
}

// ----------------------------------------------- K3: P/Q precompute ---------
__global__ __launch_bounds__(256) void k_pq(const float* __restrict__ fea,
                                            const float* __restrict__ Wf1,
                                            const float* __restrict__ bf1,
                                            float* __restrict__ Pt,
                                            float* __restrict__ Qt) {
    __shared__ __align__(16) float feaT[64][64];    // [c][n]
    __shared__ __align__(16) float WT[64][132];     // [c][o'], o' in 0..127
    __shared__ float sb[64];

    const int b = blockIdx.y;
    const int n0 = blockIdx.x * 64;
    const int tid = threadIdx.x;
    const int to = tid & 15, tn = tid >> 4;
    const float* feab = fea + (size_t)b * NCH * NPTS;

#pragma unroll
    for (int i = 0; i < 4; ++i) {
        int e = i * 1024 + tid * 4;
        int c = e >> 6, nn = e & 63;
        *(float4*)&feaT[c][nn] = *(const float4*)&feab[c * NPTS + n0 + nn];
    }
#pragma unroll
    for (int i = 0; i < 8; ++i) {
        int g = tid * 32 + i * 4;
        int op = g >> 6, c = g & 63;
        const float* src = (op < 64) ? &Wf1[op * 128 + c]
                                     : &Wf1[(op - 64) * 128 + 64 + c];
        float4 w = *(const float4*)src;
        WT[c + 0][op] = w.x; WT[c + 1][op] = w.y;
        WT[c + 2][op] = w.z; WT[c + 3][op] = w.w;
    }
    if (tid < 64) sb[tid] = bf1[tid];
    __syncthreads();

    float acc[4][8];
#pragma unroll
    for (int ni = 0; ni < 4; ++ni)
#pragma unroll
        for (int oj = 0; oj < 8; ++oj) acc[ni][oj] = 0.f;

#pragma unroll 4
    for (int c = 0; c < 64; ++c) {
        float4 a  = *(const float4*)&feaT[c][tn * 4];
        float4 w0 = *(const float4*)&WT[c][to * 8];
        float4 w1 = *(const float4*)&WT[c][to * 8 + 4];
        float av[4] = {a.x, a.y, a.z, a.w};
        float wv[8] = {w0.x, w0.y, w0.z, w0.w, w1.x, w1.y, w1.z, w1.w};
#pragma unroll
        for (int ni = 0; ni < 4; ++ni)
#pragma unroll
            for (int oj = 0; oj < 8; ++oj)
                acc[ni][oj] = fmaf(av[ni], wv[oj], acc[ni][oj]);
    }

    const int opb = to * 8;
#pragma unroll
    for (int ni = 0; ni < 4; ++ni) {
        int n = n0 + tn * 4 + ni;
        size_t base = ((size_t)b * NPTS + n) * 64;
        if (opb < 64) {     // P half: add bias
            float4 o0, o1;
            o0.x = acc[ni][0] + sb[opb + 0]; o0.y = acc[ni][1] + sb[opb + 1];
            o0.z = acc[ni][2] + sb[opb + 2]; o0.w = acc[ni][3] + sb[opb + 3];
            o1.x = acc[ni][4] + sb[opb + 4]; o1.y = acc[ni][5] + sb[opb + 5];
            o1.z = acc[ni][6] + sb[opb + 6]; o1.w = acc[ni][7] + sb[opb + 7];
            *(float4*)&Pt[base + opb]     = o0;
            *(float4*)&Pt[base + opb + 4] = o1;
        } else {            // Q half: no bias
            float4 o0, o1;
            o0.x = acc[ni][0]; o0.y = acc[ni][1]; o0.z = acc[ni][2]; o0.w = acc[ni][3];
            o1.x = acc[ni][4]; o1.y = acc[ni][5]; o1.z = acc[ni][6]; o1.w = acc[ni][7];
            *(float4*)&Qt[base + opb - 64]     = o0;
            *(float4*)&Qt[base + opb - 64 + 4] = o1;
        }
    }
}

// -------------------------------------------- K4: fused MLP + max ----------
__global__ __launch_bounds__(256) void k_mlp(
    const float* __restrict__ xyz,
    const float* __restrict__ Pt, const float* __restrict__ Qt,
    const int* __restrict__ knnidx,
    const float* __restrict__ Wg1, const float* __restrict__ bg1,
    const float* __restrict__ Wg2, const float* __restrict__ bg2,
    const float* __restrict__ Wf2, const float* __restrict__ bf2,
    const float* __restrict__ Wf3, const float* __restrict__ bf3,
    float* __restrict__ out) {
    __shared__ __align__(16) float bufX[64][68];
    __shared__ __align__(16) float bufY[64][68];
    __shared__ __align__(16) float Wbuf[64][68];
    __shared__ __align__(16) float scratch[1280];  // geo[10][68] then pm[64][17]
    __shared__ float biasS[64];
    __shared__ int sidx[64];

    const int b = blockIdx.y;
    const int n0 = blockIdx.x * 4;
    const int tid = threadIdx.x;
    const int to = tid & 15, tp = tid >> 4;

    if (tid < 64)
        sidx[tid] = knnidx[((size_t)(b * NPTS + n0)) * KNN + tid];
    __syncthreads();

    // f1 = relu(P + Q_gather) into bufX [c][pair]
    {
        int pair = tid >> 2, q = tid & 3;
        int m = sidx[pair];
        int pt = pair >> 4;
        const float* pB = &Pt[((size_t)b * NPTS + n0 + pt) * 64];
        const float* qB = &Qt[((size_t)b * NPTS + m) * 64];
#pragma unroll
        for (int i = 0; i < 4; ++i) {
            int c0 = q * 16 + i * 4;
            float4 pv = *(const float4*)&pB[c0];
            float4 qv = *(const float4*)&qB[c0];
            bufX[c0 + 0][pair] = fmaxf(pv.x + qv.x, 0.f);
            bufX[c0 + 1][pair] = fmaxf(pv.y + qv.y, 0.f);
            bufX[c0 + 2][pair] = fmaxf(pv.z + qv.z, 0.f);
            bufX[c0 + 3][pair] = fmaxf(pv.w + qv.w, 0.f);
        }
    }
    // geo [10][68] into scratch
    if (tid < 64) {
        int pair = tid, pt = pair >> 4;
        int m = sidx[pair];
        const float* xb = xyz + (size_t)b * 3 * NPTS;
        float cx = xb[0 * NPTS + n0 + pt], cy = xb[1 * NPTS + n0 + pt], cz = xb[2 * NPTS + n0 + pt];
        float kx = xb[0 * NPTS + m], ky = xb[1 * NPTS + m], kz = xb[2 * NPTS + m];
        float rx = cx - kx, ry = cy - ky, rz = cz - kz;
        float d = sqrtf(rx * rx + ry * ry + rz * rz);
        scratch[0 * 68 + pair] = d;
        scratch[1 * 68 + pair] = cx; scratch[2 * 68 + pair] = cy; scratch[3 * 68 + pair] = cz;
        scratch[4 * 68 + pair] = kx; scratch[5 * 68 + pair] = ky; scratch[6 * 68 + pair] = kz;
        scratch[7 * 68 + pair] = rx; scratch[8 * 68 + pair] = ry; scratch[9 * 68 + pair] = rz;
    }

    auto stageW = [&](const float* W, const float* bv) {
#pragma unroll
        for (int i = 0; i < 4; ++i) {
            int g = tid * 16 + i * 4;
            int o = g >> 6, c = g & 63;
            float4 w = *(const float4*)&W[g];
            Wbuf[c + 0][o] = w.x; Wbuf[c + 1][o] = w.y;
            Wbuf[c + 2][o] = w.z; Wbuf[c + 3][o] = w.w;
        }
        if (tid < 64) biasS[tid] = bv[tid];
    };

    auto gemmPh = [&](const float* src, float* dst, int Kdim) {
        float acc[4][4] = {{0.f,0.f,0.f,0.f},{0.f,0.f,0.f,0.f},
                           {0.f,0.f,0.f,0.f},{0.f,0.f,0.f,0.f}};
#pragma unroll 2
        for (int c = 0; c < Kdim; ++c) {
            float4 w = *(const float4*)&Wbuf[c][to * 4];
            float4 a = *(const float4*)(src + c * 68 + tp * 4);
            float wr[4] = {w.x, w.y, w.z, w.w};
            float ar[4] = {a.x, a.y, a.z, a.w};
#pragma unroll
            for (int oi = 0; oi < 4; ++oi)
#pragma unroll
                for (int pj = 0; pj < 4; ++pj)
                    acc[oi][pj] = fmaf(wr[oi], ar[pj], acc[oi][pj]);
        }
#pragma unroll
        for (int oi = 0; oi < 4; ++oi) {
            float bo = biasS[to * 4 + oi];
            float4 o4;
            o4.x = fmaxf(acc[oi][0] + bo, 0.f);
            o4.y = fmaxf(acc[oi][1] + bo, 0.f);
            o4.z = fmaxf(acc[oi][2] + bo, 0.f);
            o4.w = fmaxf(acc[oi][3] + bo, 0.f);
            *(float4*)(dst + (to * 4 + oi) * 68 + tp * 4) = o4;
        }
    };

    stageW(Wf2, bf2);
    __syncthreads();
    gemmPh(&bufX[0][0], &bufY[0][0], 64);       // f2
    __syncthreads();
    stageW(Wf3, bf3);
    __syncthreads();
    gemmPh(&bufY[0][0], &bufX[0][0], 64);       // f3 -> bufX
    __syncthreads();
    {   // Wg1 is 64x10
        for (int e = tid; e < 640; e += 256) {
            int o = e / 10, c = e - o * 10;
            Wbuf[c][o] = Wg1[e];
        }
        if (tid < 64) biasS[tid] = bg1[tid];
    }
    __syncthreads();
    gemmPh(scratch, &bufY[0][0], 10);           // g1 -> bufY
    __syncthreads();
    stageW(Wg2, bg2);
    __syncthreads();
    {   // g2 GEMM with fused *f3 and partial max epilogue
        float acc[4][4] = {{0.f,0.f,0.f,0.f},{0.f,0.f,0.f,0.f},
                           {0.f,0.f,0.f,0.f},{0.f,0.f,0.f,0.f}};
#pragma unroll 2
        for (int c = 0; c < 64; ++c) {
            float4 w = *(const float4*)&Wbuf[c][to * 4];
            float4 a = *(const float4*)&bufY[c][tp * 4];
            float wr[4] = {w.x, w.y, w.z, w.w};
            float ar[4] = {a.x, a.y, a.z, a.w};
#pragma unroll
            for (int oi = 0; oi < 4; ++oi)
#pragma unroll
                for (int pj = 0; pj < 4; ++pj)
                    acc[oi][pj] = fmaf(wr[oi], ar[pj], acc[oi][pj]);
        }
#pragma unroll
        for (int oi = 0; oi < 4; ++oi) {
            int o = to * 4 + oi;
            float bo = biasS[o];
            float mx = -3.0e38f;
#pragma unroll
            for (int pj = 0; pj < 4; ++pj) {
                float g2v = fmaxf(acc[oi][pj] + bo, 0.f);
                float f3v = bufX[o][tp * 4 + pj];
                mx = fmaxf(mx, g2v * f3v);
            }
            scratch[o * 17 + tp] = mx;          // pm[64][17]
        }
    }
    __syncthreads();
    {
        int o = tid & 63, pt = tid >> 6;
        float m0_ = scratch[o * 17 + pt * 4 + 0];
        float m1  = scratch[o * 17 + pt * 4 + 1];
        float m2  = scratch[o * 17 + pt * 4 + 2];
        float m3  = scratch[o * 17 + pt * 4 + 3];
        out[((size_t)b * 64 + o) * NPTS + n0 + pt] =
            fmaxf(fmaxf(m0_, m1), fmaxf(m2, m3));
    }
}

// ---------------------------------------------------------------------------
extern "C" void kernel_launch(void* const* d_in, const int* in_sizes, int n_in,
                              void* d_out, int out_size, void* d_ws, size_t ws_size,
                              hipStream_t stream) {
    const float* xyz = (const float*)d_in[0];
    const float* fea = (const float*)d_in[1];
    const float* Wg1 = (const float*)d_in[2];
    const float* bg1 = (const float*)d_in[3];
    const float* Wg2 = (const float*)d_in[4];
    const float* bg2 = (const float*)d_in[5];
    const float* Wf1 = (const float*)d_in[6];
    const float* bf1 = (const float*)d_in[7];
    const float* Wf2 = (const float*)d_in[8];
    const float* bf2 = (const float*)d_in[9];
    const float* Wf3 = (const float*)d_in[10];
    const float* bf3 = (const float*)d_in[11];
    float* out = (float*)d_out;
    float* ws = (float*)d_ws;

    float* sq = ws + WS_SQ;
    float* Pt = ws + WS_PT;
    float* Qt = ws + WS_QT;
    int* idxw = (int*)(ws + WS_IDX);

    k_sq <<<dim3(128),      dim3(256), 0, stream>>>(fea, sq);
    k_knn<<<dim3(64, 8),    dim3(256), 0, stream>>>(fea, sq, idxw);
    k_pq <<<dim3(64, 8),    dim3(256), 0, stream>>>(fea, Wf1, bf1, Pt, Qt);
    k_mlp<<<dim3(1024, 8),  dim3(256), 0, stream>>>(xyz, Pt, Qt, idxw,
                                                    Wg1, bg1, Wg2, bg2,
                                                    Wf2, bf2, Wf3, bf3, out);
}